// Round 5
// baseline (381.456 us; speedup 1.0000x reference)
//
#include <hip/hip_runtime.h>
#include <hip/hip_bf16.h>

typedef unsigned short u16;
typedef __attribute__((ext_vector_type(8))) short bf16x8;   // 8 bf16 (4 VGPRs)
typedef __attribute__((ext_vector_type(4))) float f32x4;

#define Bdim 4
#define Nseq 2048
#define DIMc 1024
#define NH   16
#define HD   64
#define F3   3072   // 3*NH*HD
#define Mrows 8192  // Bdim*Nseq

// f32 -> bf16 RNE
static __device__ __forceinline__ u16 f2b(float f) {
    union { float f; unsigned u; } v; v.f = f;
    unsigned r = v.u + 0x7fffu + ((v.u >> 16) & 1u);
    return (u16)(r >> 16);
}

static __device__ __forceinline__ bf16x8 pack8(float4 a, float4 b) {
    bf16x8 r;
    r[0] = (short)f2b(a.x); r[1] = (short)f2b(a.y); r[2] = (short)f2b(a.z); r[3] = (short)f2b(a.w);
    r[4] = (short)f2b(b.x); r[5] = (short)f2b(b.y); r[6] = (short)f2b(b.z); r[7] = (short)f2b(b.w);
    return r;
}

// Normalize a 0/1 mask buffer of unknown dtype (int32 / float32 / uint8) to int32.
__global__ __launch_bounds__(256) void norm_mask_kernel(const void* __restrict__ raw, int n,
                                                        int* __restrict__ outm) {
    const unsigned* as_u = (const unsigned*)raw;
    const float* as_f = (const float*)raw;
    const unsigned char* as_b = (const unsigned char*)raw;
    int ns = n < 512 ? n : 512;
    bool ok_i = true, ok_f = true;
    for (int i = 0; i < ns; ++i) {
        unsigned v = as_u[i];
        ok_i &= (v <= 1u);
        ok_f &= (v == 0u) || (v == 0x3f800000u);
    }
    const int mode = ok_i ? 0 : (ok_f ? 1 : 2);
    int i = blockIdx.x * 256 + threadIdx.x;
    if (i < n) {
        int v;
        if (mode == 0) v = (int)as_u[i];
        else if (mode == 1) v = (as_f[i] != 0.f) ? 1 : 0;
        else v = (int)as_b[i];
        outm[i] = (v != 0) ? 1 : 0;
    }
}

// ===== MFMA QKV GEMM =====
// C[m][f] = sum_k A[m][k] * W[f][k]; A,W f32, converted to bf16 during LDS staging.
// 128x128 tile, BK=32, 4 waves 2x2, each wave 64x64 (4x4 frags of 16x16x32).
__global__ __launch_bounds__(256, 2) void qkv_gemm_kernel(const float* __restrict__ A,
                                                          const float* __restrict__ Bw,
                                                          u16* __restrict__ C) {
    __shared__ u16 As[128][40];
    __shared__ u16 Bs[128][40];
    const int t = threadIdx.x;
    const int lane = t & 63;
    const int wave = t >> 6;
    const int wr = (wave >> 1) * 64;
    const int wc = (wave & 1) * 64;
    const int row0 = blockIdx.x * 128;
    const int col0 = blockIdx.y * 128;

    const int lr = lane & 15;          // A/B frag row index
    const int lk = (lane >> 4) * 8;    // frag k offset
    const int cr = (lane >> 4) * 4;    // C frag row base
    const int cc = lane & 15;          // C frag col

    const f32x4 fzero = {0.f, 0.f, 0.f, 0.f};
    f32x4 acc[4][4];
#pragma unroll
    for (int i = 0; i < 4; ++i)
#pragma unroll
        for (int j = 0; j < 4; ++j) acc[i][j] = fzero;

    const int sr = t >> 2;
    const int sc = (t & 3) * 8;

    for (int k0 = 0; k0 < DIMc; k0 += 32) {
#pragma unroll
        for (int p = 0; p < 2; ++p) {
            int r = sr + p * 64;
            const float* ap = A + (size_t)(row0 + r) * DIMc + k0 + sc;
            const float* bp = Bw + (size_t)(col0 + r) * DIMc + k0 + sc;
            *reinterpret_cast<bf16x8*>(&As[r][sc]) =
                pack8(*reinterpret_cast<const float4*>(ap), *reinterpret_cast<const float4*>(ap + 4));
            *reinterpret_cast<bf16x8*>(&Bs[r][sc]) =
                pack8(*reinterpret_cast<const float4*>(bp), *reinterpret_cast<const float4*>(bp + 4));
        }
        __syncthreads();
        bf16x8 af[4], bfr[4];
#pragma unroll
        for (int i = 0; i < 4; ++i) {
            af[i]  = *reinterpret_cast<const bf16x8*>(&As[wr + i * 16 + lr][lk]);
            bfr[i] = *reinterpret_cast<const bf16x8*>(&Bs[wc + i * 16 + lr][lk]);
        }
#pragma unroll
        for (int mi = 0; mi < 4; ++mi)
#pragma unroll
            for (int ni = 0; ni < 4; ++ni)
                acc[mi][ni] = __builtin_amdgcn_mfma_f32_16x16x32_bf16(af[mi], bfr[ni], acc[mi][ni], 0, 0, 0);
        __syncthreads();
    }

#pragma unroll
    for (int mi = 0; mi < 4; ++mi)
#pragma unroll
        for (int ni = 0; ni < 4; ++ni)
#pragma unroll
            for (int j = 0; j < 4; ++j) {
                int r = row0 + wr + mi * 16 + cr + j;
                int c = col0 + wc + ni * 16 + cc;
                C[(size_t)r * F3 + c] = f2b(acc[mi][ni][j]);
            }
}

// ===== MFMA flash attention; OUTPUT IS FLOAT32 =====
// Block = (b, h, q-tile of 128). 4 waves x 32 q-rows.
__global__ __launch_bounds__(256, 2) void attn_kernel(const u16* __restrict__ qkv,
                                                      const int* __restrict__ key_mask,
                                                      const int* __restrict__ query_mask,
                                                      const int* __restrict__ causal_p,
                                                      float* __restrict__ out) {
    const int bh = blockIdx.x;
    const int qt = blockIdx.y;
    const int b = bh >> 4;
    const int h = bh & 15;
    const int t = threadIdx.x;
    const int lane = t & 63;
    const int wave = t >> 6;
    const int causal = causal_p[0];

    __shared__ u16 Ks[64][72];       // K tile, row-major, +8 pad
    __shared__ u16 Vt[64][72];       // V tile TRANSPOSED: Vt[d][m]
    __shared__ u16 Ps[4][32][72];    // per-wave P round-trip (C-layout -> A-layout)

    const int q0 = qt * 128;
    const int wq0 = q0 + wave * 32;
    const int lr = lane & 15;
    const int lk = (lane >> 4) * 8;
    const int cr = (lane >> 4) * 4;
    const int cc = lane & 15;

    const f32x4 fzero = {0.f, 0.f, 0.f, 0.f};

    bf16x8 qf[2][2];
#pragma unroll
    for (int mf = 0; mf < 2; ++mf)
#pragma unroll
        for (int ks = 0; ks < 2; ++ks)
            qf[mf][ks] = *reinterpret_cast<const bf16x8*>(
                qkv + (size_t)(b * Nseq + wq0 + mf * 16 + lr) * F3 + h * HD + ks * 32 + lk);

    float mrow[2][4], lsum[2][4];
    f32x4 oacc[2][4];
    int qm[2][4];
#pragma unroll
    for (int mf = 0; mf < 2; ++mf)
#pragma unroll
        for (int j = 0; j < 4; ++j) {
            mrow[mf][j] = -1e30f;
            lsum[mf][j] = 0.f;
            qm[mf][j] = query_mask[b * Nseq + wq0 + mf * 16 + cr + j];
        }
#pragma unroll
    for (int mf = 0; mf < 2; ++mf)
#pragma unroll
        for (int df = 0; df < 4; ++df) oacc[mf][df] = fzero;

    const int kvend = causal ? (q0 + 128) : Nseq;
    const int sr = t >> 2;
    const int sc = (t & 3) * 8;

    for (int m0 = 0; m0 < kvend; m0 += 64) {
        const u16* krow = qkv + (size_t)(b * Nseq + m0 + sr) * F3 + DIMc + h * HD;
        const u16* vrow = krow + DIMc;
        *reinterpret_cast<bf16x8*>(&Ks[sr][sc])      = *reinterpret_cast<const bf16x8*>(krow + sc);
        *reinterpret_cast<bf16x8*>(&Ks[sr][sc + 32]) = *reinterpret_cast<const bf16x8*>(krow + sc + 32);
        bf16x8 v0 = *reinterpret_cast<const bf16x8*>(vrow + sc);
        bf16x8 v1 = *reinterpret_cast<const bf16x8*>(vrow + sc + 32);
#pragma unroll
        for (int e = 0; e < 8; ++e) {
            Vt[sc + e][sr]      = (u16)v0[e];
            Vt[sc + 32 + e][sr] = (u16)v1[e];
        }
        __syncthreads();

        // ---- S = Q K^T ----
        f32x4 sacc[2][4];
#pragma unroll
        for (int mf = 0; mf < 2; ++mf)
#pragma unroll
            for (int nf = 0; nf < 4; ++nf) sacc[mf][nf] = fzero;
        bf16x8 kf[4][2];
#pragma unroll
        for (int nf = 0; nf < 4; ++nf)
#pragma unroll
            for (int ks = 0; ks < 2; ++ks)
                kf[nf][ks] = *reinterpret_cast<const bf16x8*>(&Ks[nf * 16 + lr][ks * 32 + lk]);
#pragma unroll
        for (int mf = 0; mf < 2; ++mf)
#pragma unroll
            for (int nf = 0; nf < 4; ++nf) {
                sacc[mf][nf] = __builtin_amdgcn_mfma_f32_16x16x32_bf16(qf[mf][0], kf[nf][0], sacc[mf][nf], 0, 0, 0);
                sacc[mf][nf] = __builtin_amdgcn_mfma_f32_16x16x32_bf16(qf[mf][1], kf[nf][1], sacc[mf][nf], 0, 0, 0);
            }

        int km[4];
#pragma unroll
        for (int nf = 0; nf < 4; ++nf) km[nf] = key_mask[b * Nseq + m0 + nf * 16 + cc];

        // ---- masked online softmax ----
#pragma unroll
        for (int mf = 0; mf < 2; ++mf) {
            float p[4][4];
#pragma unroll
            for (int j = 0; j < 4; ++j) {
                const int nrow = wq0 + mf * 16 + cr + j;
                float mx = -1e30f;
#pragma unroll
                for (int nf = 0; nf < 4; ++nf) {
                    float s = sacc[mf][nf][j] * 0.125f;
                    const int mcol = m0 + nf * 16 + cc;
                    const bool ok = (km[nf] != 0) && (qm[mf][j] != 0) && (!causal || mcol <= nrow);
                    s = ok ? s : -1e30f;
                    p[nf][j] = s;
                    mx = fmaxf(mx, s);
                }
#pragma unroll
                for (int off = 1; off < 16; off <<= 1) mx = fmaxf(mx, __shfl_xor(mx, off));
                const float mnew = fmaxf(mrow[mf][j], mx);
                const float scale = __expf(mrow[mf][j] - mnew);
                float rs = 0.f;
#pragma unroll
                for (int nf = 0; nf < 4; ++nf) {
                    float pv = (p[nf][j] > -1e29f) ? __expf(p[nf][j] - mnew) : 0.f;
                    p[nf][j] = pv;
                    rs += pv;
                }
#pragma unroll
                for (int off = 1; off < 16; off <<= 1) rs += __shfl_xor(rs, off);
                lsum[mf][j] = lsum[mf][j] * scale + rs;
                mrow[mf][j] = mnew;
#pragma unroll
                for (int df = 0; df < 4; ++df) oacc[mf][df][j] *= scale;
            }
#pragma unroll
            for (int nf = 0; nf < 4; ++nf)
#pragma unroll
                for (int j = 0; j < 4; ++j)
                    Ps[wave][mf * 16 + cr + j][nf * 16 + cc] = f2b(p[nf][j]);
        }

        // ---- O += P V ----
        bf16x8 vb[2][4];
#pragma unroll
        for (int ks = 0; ks < 2; ++ks)
#pragma unroll
            for (int df = 0; df < 4; ++df)
                vb[ks][df] = *reinterpret_cast<const bf16x8*>(&Vt[df * 16 + lr][ks * 32 + lk]);
#pragma unroll
        for (int mf = 0; mf < 2; ++mf) {
            bf16x8 pa0 = *reinterpret_cast<const bf16x8*>(&Ps[wave][mf * 16 + lr][lk]);
            bf16x8 pa1 = *reinterpret_cast<const bf16x8*>(&Ps[wave][mf * 16 + lr][32 + lk]);
#pragma unroll
            for (int df = 0; df < 4; ++df) {
                oacc[mf][df] = __builtin_amdgcn_mfma_f32_16x16x32_bf16(pa0, vb[0][df], oacc[mf][df], 0, 0, 0);
                oacc[mf][df] = __builtin_amdgcn_mfma_f32_16x16x32_bf16(pa1, vb[1][df], oacc[mf][df], 0, 0, 0);
            }
        }
        __syncthreads();
    }

    // ---- epilogue: normalize; fully-masked rows -> 0; WRITE FLOAT32 ----
#pragma unroll
    for (int mf = 0; mf < 2; ++mf)
#pragma unroll
        for (int j = 0; j < 4; ++j) {
            const int n = wq0 + mf * 16 + cr + j;
            const float inv = (mrow[mf][j] > -1e29f && lsum[mf][j] > 0.f) ? 1.f / lsum[mf][j] : 0.f;
#pragma unroll
            for (int df = 0; df < 4; ++df)
                out[(size_t)(b * Nseq + n) * DIMc + h * HD + df * 16 + cc] = oacc[mf][df][j] * inv;
        }
}

extern "C" void kernel_launch(void* const* d_in, const int* in_sizes, int n_in,
                              void* d_out, int out_size, void* d_ws, size_t ws_size,
                              hipStream_t stream) {
    const float* x = (const float*)d_in[0];       // [4,2048,1024] f32
    const float* W = (const float*)d_in[1];       // [3072,1024] f32

    char* ws = (char*)d_ws;
    int* km_n = (int*)(ws);
    int* qm_n = (int*)(ws + 32 * 1024);
    int* ca_n = (int*)(ws + 64 * 1024);
    u16* qkv  = (u16*)(ws + (size_t)1024 * 1024);  // 48 MiB bf16 [8192][3072]

    const int nm = Bdim * Nseq;
    norm_mask_kernel<<<(nm + 255) / 256, 256, 0, stream>>>(d_in[2], nm, km_n);
    norm_mask_kernel<<<(nm + 255) / 256, 256, 0, stream>>>(d_in[3], nm, qm_n);
    norm_mask_kernel<<<1, 256, 0, stream>>>(d_in[4], 1, ca_n);

    qkv_gemm_kernel<<<dim3(Mrows / 128, F3 / 128), 256, 0, stream>>>(x, W, qkv);

    attn_kernel<<<dim3(Bdim * NH, Nseq / 128), 256, 0, stream>>>(qkv, km_n, qm_n, ca_n,
                                                                 (float*)d_out);
}

// Round 6
// 268.945 us; speedup vs baseline: 1.4183x; 1.4183x over previous
//
#include <hip/hip_runtime.h>
#include <hip/hip_bf16.h>

typedef unsigned short u16;
typedef __attribute__((ext_vector_type(8))) short bf16x8;   // 8 bf16 (4 VGPRs)
typedef __attribute__((ext_vector_type(4))) float f32x4;

#define Bdim 4
#define Nseq 2048
#define DIMc 1024
#define NH   16
#define HD   64
#define F3   3072   // 3*NH*HD
#define Mrows 8192  // Bdim*Nseq

// f32 -> bf16 RNE
static __device__ __forceinline__ u16 f2b(float f) {
    union { float f; unsigned u; } v; v.f = f;
    unsigned r = v.u + 0x7fffu + ((v.u >> 16) & 1u);
    return (u16)(r >> 16);
}

__global__ __launch_bounds__(256) void cast_f32_bf16_kernel(const float* __restrict__ in,
                                                            u16* __restrict__ out, int n4) {
    int i = blockIdx.x * 256 + threadIdx.x;
    if (i >= n4) return;
    float4 v = reinterpret_cast<const float4*>(in)[i];
    ushort4 o;
    o.x = f2b(v.x); o.y = f2b(v.y); o.z = f2b(v.z); o.w = f2b(v.w);
    reinterpret_cast<ushort4*>(out)[i] = o;
}

// Normalize a 0/1 mask buffer of unknown dtype (int32 / float32 / uint8) to int32.
__global__ __launch_bounds__(256) void norm_mask_kernel(const void* __restrict__ raw, int n,
                                                        int* __restrict__ outm) {
    const unsigned* as_u = (const unsigned*)raw;
    const float* as_f = (const float*)raw;
    const unsigned char* as_b = (const unsigned char*)raw;
    int ns = n < 512 ? n : 512;
    bool ok_i = true, ok_f = true;
    for (int i = 0; i < ns; ++i) {
        unsigned v = as_u[i];
        ok_i &= (v <= 1u);
        ok_f &= (v == 0u) || (v == 0x3f800000u);
    }
    const int mode = ok_i ? 0 : (ok_f ? 1 : 2);
    int i = blockIdx.x * 256 + threadIdx.x;
    if (i < n) {
        int v;
        if (mode == 0) v = (int)as_u[i];
        else if (mode == 1) v = (as_f[i] != 0.f) ? 1 : 0;
        else v = (int)as_b[i];
        outm[i] = (v != 0) ? 1 : 0;
    }
}

// ===== MFMA QKV GEMM, bf16 inputs, BK=64, 128x128 tile =====
// C[m][f] = sum_k A[m][k] * W[f][k]
__global__ __launch_bounds__(256, 2) void qkv_gemm_kernel(const u16* __restrict__ A,
                                                          const u16* __restrict__ Bw,
                                                          u16* __restrict__ C) {
    __shared__ u16 As[128][72];
    __shared__ u16 Bs[128][72];
    const int t = threadIdx.x;
    const int lane = t & 63;
    const int wave = t >> 6;
    const int wr = (wave >> 1) * 64;
    const int wc = (wave & 1) * 64;
    const int row0 = blockIdx.x * 128;
    const int col0 = blockIdx.y * 128;

    const int lr = lane & 15;          // A/B frag row index
    const int lk = (lane >> 4) * 8;    // frag k offset
    const int cr = (lane >> 4) * 4;    // C frag row base
    const int cc = lane & 15;          // C frag col

    const f32x4 fzero = {0.f, 0.f, 0.f, 0.f};
    f32x4 acc[4][4];
#pragma unroll
    for (int i = 0; i < 4; ++i)
#pragma unroll
        for (int j = 0; j < 4; ++j) acc[i][j] = fzero;

    const int strow = t >> 3;          // 0..31
    const int stcol = (t & 7) * 8;     // 0..56

    for (int k0 = 0; k0 < DIMc; k0 += 64) {
        __syncthreads();
#pragma unroll
        for (int it = 0; it < 4; ++it) {
            const int r = it * 32 + strow;
            *reinterpret_cast<bf16x8*>(&As[r][stcol]) =
                *reinterpret_cast<const bf16x8*>(A + (size_t)(row0 + r) * DIMc + k0 + stcol);
            *reinterpret_cast<bf16x8*>(&Bs[r][stcol]) =
                *reinterpret_cast<const bf16x8*>(Bw + (size_t)(col0 + r) * DIMc + k0 + stcol);
        }
        __syncthreads();

        bf16x8 af[4][2], bfr[4][2];
#pragma unroll
        for (int i = 0; i < 4; ++i)
#pragma unroll
            for (int ks = 0; ks < 2; ++ks) {
                af[i][ks]  = *reinterpret_cast<const bf16x8*>(&As[wr + i * 16 + lr][ks * 32 + lk]);
                bfr[i][ks] = *reinterpret_cast<const bf16x8*>(&Bs[wc + i * 16 + lr][ks * 32 + lk]);
            }
#pragma unroll
        for (int ks = 0; ks < 2; ++ks)
#pragma unroll
            for (int mi = 0; mi < 4; ++mi)
#pragma unroll
                for (int ni = 0; ni < 4; ++ni)
                    acc[mi][ni] = __builtin_amdgcn_mfma_f32_16x16x32_bf16(af[mi][ks], bfr[ni][ks], acc[mi][ni], 0, 0, 0);
    }

#pragma unroll
    for (int mi = 0; mi < 4; ++mi)
#pragma unroll
        for (int ni = 0; ni < 4; ++ni)
#pragma unroll
            for (int j = 0; j < 4; ++j) {
                int r = row0 + wr + mi * 16 + cr + j;
                int c = col0 + wc + ni * 16 + cc;
                C[(size_t)r * F3 + c] = f2b(acc[mi][ni][j]);
            }
}

// ===== MFMA flash attention, swapped-operand softmax (S^T), O^T accumulation =====
// Block = (b, h, q-tile of 128). 4 waves x 32 q-rows. Output f32.
__global__ __launch_bounds__(256, 2) void attn_kernel(const u16* __restrict__ qkv,
                                                      const int* __restrict__ key_mask,
                                                      const int* __restrict__ query_mask,
                                                      const int* __restrict__ causal_p,
                                                      float* __restrict__ out) {
    const int bh = blockIdx.x;
    const int qt = blockIdx.y;
    const int b = bh >> 4;
    const int h = bh & 15;
    const int t = threadIdx.x;
    const int lane = t & 63;
    const int wave = t >> 6;
    const int g = lane >> 4;       // 4-lane-group index 0..3
    const int lq = lane & 15;      // q (col) index within a 16-frag
    const int causal = causal_p[0];

    __shared__ u16 Ks[64][72];       // K tile row-major [m][d], +8 pad
    __shared__ u16 Vt[64][72];       // V tile transposed [d][m]
    __shared__ u16 Ps[4][32][72];    // per-wave P [q][k], +8 pad

    const int q0 = qt * 128;
    const int wq0 = q0 + wave * 32;

    const f32x4 fzero = {0.f, 0.f, 0.f, 0.f};

    // Q fragments (B-operand layout = rows of Q): q = wq0 + qf*16 + lq, d = ks*32 + g*8 + e
    bf16x8 qfr[2][2];
#pragma unroll
    for (int qf = 0; qf < 2; ++qf)
#pragma unroll
        for (int ks = 0; ks < 2; ++ks)
            qfr[qf][ks] = *reinterpret_cast<const bf16x8*>(
                qkv + (size_t)(b * Nseq + wq0 + qf * 16 + lq) * F3 + h * HD + ks * 32 + g * 8);

    int qmv[2];
    float mrow[2], lsum[2];
    f32x4 oacc[4][2];   // [df][qf]: O^T[d = df*16 + g*4 + r][q = qf*16 + lq]
#pragma unroll
    for (int qf = 0; qf < 2; ++qf) {
        qmv[qf] = query_mask[b * Nseq + wq0 + qf * 16 + lq];
        mrow[qf] = -1e30f;
        lsum[qf] = 0.f;
    }
#pragma unroll
    for (int df = 0; df < 4; ++df)
#pragma unroll
        for (int qf = 0; qf < 2; ++qf) oacc[df][qf] = fzero;

    const int kvend = causal ? (q0 + 128) : Nseq;
    const int sr = t >> 2;           // K staging row 0..63
    const int sc = (t & 3) * 8;      // K staging col {0,8,16,24}

    for (int m0 = 0; m0 < kvend; m0 += 64) {
        // ---- stage K (row-major, b128 writes) ----
        const u16* krow = qkv + (size_t)(b * Nseq + m0 + sr) * F3 + DIMc + h * HD;
        *reinterpret_cast<bf16x8*>(&Ks[sr][sc])      = *reinterpret_cast<const bf16x8*>(krow + sc);
        *reinterpret_cast<bf16x8*>(&Ks[sr][sc + 32]) = *reinterpret_cast<const bf16x8*>(krow + sc + 32);
        // ---- stage V transposed: wave stages d-rows [16w,16w+16), m = lane ----
        {
            const u16* vrow = qkv + (size_t)(b * Nseq + m0 + lane) * F3 + 2 * DIMc + h * HD + wave * 16;
            bf16x8 v0 = *reinterpret_cast<const bf16x8*>(vrow);
            bf16x8 v1 = *reinterpret_cast<const bf16x8*>(vrow + 8);
#pragma unroll
            for (int e = 0; e < 8; ++e) {
                Vt[wave * 16 + e][lane]     = (u16)v0[e];
                Vt[wave * 16 + 8 + e][lane] = (u16)v1[e];
            }
        }
        __syncthreads();

        // ---- S^T = K Q^T : sacc[kf][qf], lane holds q = lq, kk = kf*16 + g*4 + r ----
        f32x4 sacc[4][2];
#pragma unroll
        for (int kf = 0; kf < 4; ++kf)
#pragma unroll
            for (int qf = 0; qf < 2; ++qf) sacc[kf][qf] = fzero;
        bf16x8 ka[4][2];
#pragma unroll
        for (int kf = 0; kf < 4; ++kf)
#pragma unroll
            for (int ks = 0; ks < 2; ++ks)
                ka[kf][ks] = *reinterpret_cast<const bf16x8*>(&Ks[kf * 16 + lq][ks * 32 + g * 8]);
#pragma unroll
        for (int kf = 0; kf < 4; ++kf)
#pragma unroll
            for (int qf = 0; qf < 2; ++qf) {
                sacc[kf][qf] = __builtin_amdgcn_mfma_f32_16x16x32_bf16(ka[kf][0], qfr[qf][0], sacc[kf][qf], 0, 0, 0);
                sacc[kf][qf] = __builtin_amdgcn_mfma_f32_16x16x32_bf16(ka[kf][1], qfr[qf][1], sacc[kf][qf], 0, 0, 0);
            }

        // ---- key mask: lane's k rows are kf*16 + g*4 + {0..3} ----
        int4 km4[4];
#pragma unroll
        for (int kf = 0; kf < 4; ++kf)
            km4[kf] = *reinterpret_cast<const int4*>(key_mask + b * Nseq + m0 + kf * 16 + g * 4);

        // ---- softmax: in-lane over 16 scores + 2 cross-group shuffles ----
#pragma unroll
        for (int qf = 0; qf < 2; ++qf) {
            const int qg = wq0 + qf * 16 + lq;
            const bool qok = (qmv[qf] != 0);
            float s[4][4];
            float mx = -1e30f;
#pragma unroll
            for (int kf = 0; kf < 4; ++kf) {
                const int* kmr = reinterpret_cast<const int*>(&km4[kf]);
#pragma unroll
                for (int r = 0; r < 4; ++r) {
                    const int kg = m0 + kf * 16 + g * 4 + r;
                    float sv = sacc[kf][qf][r] * 0.125f;   // 1/sqrt(64)
                    const bool ok = qok && (kmr[r] != 0) && (!causal || kg <= qg);
                    sv = ok ? sv : -1e30f;
                    s[kf][r] = sv;
                    mx = fmaxf(mx, sv);
                }
            }
            mx = fmaxf(mx, __shfl_xor(mx, 16));
            mx = fmaxf(mx, __shfl_xor(mx, 32));
            const float mnew = fmaxf(mrow[qf], mx);
            const float scale = __expf(mrow[qf] - mnew);
            float rs = 0.f;
#pragma unroll
            for (int kf = 0; kf < 4; ++kf)
#pragma unroll
                for (int r = 0; r < 4; ++r) {
                    const float pv = (s[kf][r] > -1e29f) ? __expf(s[kf][r] - mnew) : 0.f;
                    s[kf][r] = pv;
                    rs += pv;
                }
            rs += __shfl_xor(rs, 16);
            rs += __shfl_xor(rs, 32);
            lsum[qf] = lsum[qf] * scale + rs;
            mrow[qf] = mnew;
#pragma unroll
            for (int df = 0; df < 4; ++df) oacc[df][qf] *= scale;
            // P -> LDS in [q][k] layout (2-way banks only)
#pragma unroll
            for (int kf = 0; kf < 4; ++kf)
#pragma unroll
                for (int r = 0; r < 4; ++r)
                    Ps[wave][qf * 16 + lq][kf * 16 + g * 4 + r] = f2b(s[kf][r]);
        }

        // ---- O^T += V^T P^T (A = Vt rows, B = Ps rows; wave-local Ps, no barrier) ----
        bf16x8 va[4][2], pb[2][2];
#pragma unroll
        for (int df = 0; df < 4; ++df)
#pragma unroll
            for (int kc = 0; kc < 2; ++kc)
                va[df][kc] = *reinterpret_cast<const bf16x8*>(&Vt[df * 16 + lq][kc * 32 + g * 8]);
#pragma unroll
        for (int qf = 0; qf < 2; ++qf)
#pragma unroll
            for (int kc = 0; kc < 2; ++kc)
                pb[qf][kc] = *reinterpret_cast<const bf16x8*>(&Ps[wave][qf * 16 + lq][kc * 32 + g * 8]);
#pragma unroll
        for (int df = 0; df < 4; ++df)
#pragma unroll
            for (int qf = 0; qf < 2; ++qf) {
                oacc[df][qf] = __builtin_amdgcn_mfma_f32_16x16x32_bf16(va[df][0], pb[qf][0], oacc[df][qf], 0, 0, 0);
                oacc[df][qf] = __builtin_amdgcn_mfma_f32_16x16x32_bf16(va[df][1], pb[qf][1], oacc[df][qf], 0, 0, 0);
            }
        __syncthreads();
    }

    // ---- epilogue: normalize (in-lane state); fully-masked rows -> 0; f32 writes ----
#pragma unroll
    for (int qf = 0; qf < 2; ++qf) {
        const float inv = (mrow[qf] > -1e29f && lsum[qf] > 0.f) ? 1.f / lsum[qf] : 0.f;
        const size_t rowoff = (size_t)(b * Nseq + wq0 + qf * 16 + lq) * DIMc + h * HD;
#pragma unroll
        for (int df = 0; df < 4; ++df)
#pragma unroll
            for (int r = 0; r < 4; ++r)
                out[rowoff + df * 16 + g * 4 + r] = oacc[df][qf][r] * inv;
    }
}

extern "C" void kernel_launch(void* const* d_in, const int* in_sizes, int n_in,
                              void* d_out, int out_size, void* d_ws, size_t ws_size,
                              hipStream_t stream) {
    const float* x = (const float*)d_in[0];       // [4,2048,1024] f32
    const float* W = (const float*)d_in[1];       // [3072,1024] f32

    char* ws = (char*)d_ws;
    int* km_n = (int*)(ws);
    int* qm_n = (int*)(ws + 32 * 1024);
    int* ca_n = (int*)(ws + 64 * 1024);
    u16* qkv  = (u16*)(ws + (size_t)1024 * 1024);             // 48 MiB
    u16* xb   = (u16*)(ws + (size_t)49 * 1024 * 1024);        // 16 MiB
    u16* wb   = (u16*)(ws + (size_t)65 * 1024 * 1024);        //  6 MiB

    const int nm = Bdim * Nseq;
    norm_mask_kernel<<<(nm + 255) / 256, 256, 0, stream>>>(d_in[2], nm, km_n);
    norm_mask_kernel<<<(nm + 255) / 256, 256, 0, stream>>>(d_in[3], nm, qm_n);
    norm_mask_kernel<<<1, 256, 0, stream>>>(d_in[4], 1, ca_n);

    const int nx4 = (Mrows * DIMc) / 4;
    const int nw4 = (F3 * DIMc) / 4;
    cast_f32_bf16_kernel<<<(nx4 + 255) / 256, 256, 0, stream>>>(x, xb, nx4);
    cast_f32_bf16_kernel<<<(nw4 + 255) / 256, 256, 0, stream>>>(W, wb, nw4);

    qkv_gemm_kernel<<<dim3(Mrows / 128, F3 / 128), 256, 0, stream>>>(xb, wb, qkv);

    attn_kernel<<<dim3(Bdim * NH, Nseq / 128), 256, 0, stream>>>(qkv, km_n, qm_n, ca_n,
                                                                 (float*)d_out);
}

// Round 7
// 244.046 us; speedup vs baseline: 1.5630x; 1.1020x over previous
//
#include <hip/hip_runtime.h>
#include <hip/hip_bf16.h>

typedef unsigned short u16;
typedef __attribute__((ext_vector_type(8))) short bf16x8;   // 8 bf16 (4 VGPRs)
typedef __attribute__((ext_vector_type(4))) float f32x4;

#define Bdim 4
#define Nseq 2048
#define DIMc 1024
#define NH   16
#define HD   64
#define F3   3072   // 3*NH*HD
#define Mrows 8192  // Bdim*Nseq

typedef const __attribute__((address_space(1))) unsigned int gl_u32;
typedef __attribute__((address_space(3))) unsigned int lds_u32;

// f32 -> bf16 RNE
static __device__ __forceinline__ u16 f2b(float f) {
    union { float f; unsigned u; } v; v.f = f;
    unsigned r = v.u + 0x7fffu + ((v.u >> 16) & 1u);
    return (u16)(r >> 16);
}

__global__ __launch_bounds__(256) void cast_f32_bf16_kernel(const float* __restrict__ in,
                                                            u16* __restrict__ out, int n4) {
    int i = blockIdx.x * 256 + threadIdx.x;
    if (i >= n4) return;
    float4 v = reinterpret_cast<const float4*>(in)[i];
    ushort4 o;
    o.x = f2b(v.x); o.y = f2b(v.y); o.z = f2b(v.z); o.w = f2b(v.w);
    reinterpret_cast<ushort4*>(out)[i] = o;
}

// Normalize a 0/1 mask buffer of unknown dtype (int32 / float32 / uint8) to int32.
__global__ __launch_bounds__(256) void norm_mask_kernel(const void* __restrict__ raw, int n,
                                                        int* __restrict__ outm) {
    const unsigned* as_u = (const unsigned*)raw;
    const float* as_f = (const float*)raw;
    const unsigned char* as_b = (const unsigned char*)raw;
    int ns = n < 512 ? n : 512;
    bool ok_i = true, ok_f = true;
    for (int i = 0; i < ns; ++i) {
        unsigned v = as_u[i];
        ok_i &= (v <= 1u);
        ok_f &= (v == 0u) || (v == 0x3f800000u);
    }
    const int mode = ok_i ? 0 : (ok_f ? 1 : 2);
    int i = blockIdx.x * 256 + threadIdx.x;
    if (i < n) {
        int v;
        if (mode == 0) v = (int)as_u[i];
        else if (mode == 1) v = (as_f[i] != 0.f) ? 1 : 0;
        else v = (int)as_b[i];
        outm[i] = (v != 0) ? 1 : 0;
    }
}

// ===== MFMA QKV GEMM, m97-style: global_load_lds w16, linear LDS, BK=32 =====
// C[m][f] = sum_k A[m][k] * W[f][k]
__global__ __launch_bounds__(256, 2) void qkv_gemm_kernel(const u16* __restrict__ A,
                                                          const u16* __restrict__ Bw,
                                                          u16* __restrict__ C) {
    __shared__ u16 As[128 * 32];   // linear, row stride 32 u16 (64 B)
    __shared__ u16 Bs[128 * 32];
    const int t = threadIdx.x;
    const int lane = t & 63;
    const int wave = t >> 6;
    const int wr = (wave >> 1) * 64;
    const int wc = (wave & 1) * 64;
    const int row0 = blockIdx.x * 128;
    const int col0 = blockIdx.y * 128;

    const int lr = lane & 15;          // A/B frag row index
    const int lk = (lane >> 4) * 8;    // frag k offset (u16)
    const int cr = (lane >> 4) * 4;    // C frag row base
    const int cc = lane & 15;          // C frag col

    const f32x4 fzero = {0.f, 0.f, 0.f, 0.f};
    f32x4 acc[4][4];
#pragma unroll
    for (int i = 0; i < 4; ++i)
#pragma unroll
        for (int j = 0; j < 4; ++j) acc[i][j] = fzero;

    // staging geometry: wave stages 16 rows/issue (64 B rows), lane -> row wave*16+(lane>>2), 16B chunk (lane&3)
    const int strow = wave * 16 + (lane >> 2);
    const int stcol = (lane & 3) * 8;   // u16 col within 32-u16 row

    for (int k0 = 0; k0 < DIMc; k0 += 32) {
        __syncthreads();   // previous compute finished reading LDS
#pragma unroll
        for (int issue = 0; issue < 2; ++issue) {
            const int r = issue * 64 + strow;
            __builtin_amdgcn_global_load_lds(
                (gl_u32*)(A + (size_t)(row0 + r) * DIMc + k0 + stcol),
                (lds_u32*)(As + (size_t)(issue * 64 + wave * 16) * 32), 16, 0, 0);
            __builtin_amdgcn_global_load_lds(
                (gl_u32*)(Bw + (size_t)(col0 + r) * DIMc + k0 + stcol),
                (lds_u32*)(Bs + (size_t)(issue * 64 + wave * 16) * 32), 16, 0, 0);
        }
        __syncthreads();   // vmcnt(0) drain + visibility

        bf16x8 af[4], bfr[4];
#pragma unroll
        for (int i = 0; i < 4; ++i) {
            af[i]  = *reinterpret_cast<const bf16x8*>(&As[(wr + i * 16 + lr) * 32 + lk]);
            bfr[i] = *reinterpret_cast<const bf16x8*>(&Bs[(wc + i * 16 + lr) * 32 + lk]);
        }
#pragma unroll
        for (int mi = 0; mi < 4; ++mi)
#pragma unroll
            for (int ni = 0; ni < 4; ++ni)
                acc[mi][ni] = __builtin_amdgcn_mfma_f32_16x16x32_bf16(af[mi], bfr[ni], acc[mi][ni], 0, 0, 0);
    }

#pragma unroll
    for (int mi = 0; mi < 4; ++mi)
#pragma unroll
        for (int ni = 0; ni < 4; ++ni)
#pragma unroll
            for (int j = 0; j < 4; ++j) {
                int r = row0 + wr + mi * 16 + cr + j;
                int c = col0 + wc + ni * 16 + cc;
                C[(size_t)r * F3 + c] = f2b(acc[mi][ni][j]);
            }
}

// ===== per-tile attention compute (all indices compile-time after inlining) =====
static __device__ __forceinline__ void attn_tile_compute(
    const bf16x8 (&qfr)[2][2], const int (&qmv)[2],
    float (&mrow)[2], float (&lsum)[2], f32x4 (&oacc)[4][2],
    const bf16x8 (&ka)[4][2], const bf16x8 (&va)[4][2],
    const int (&km)[4][4],
    int wq0, int m0, int causal,
    u16 (*Psw)[72], int g, int lq)
{
    const f32x4 fzero = {0.f, 0.f, 0.f, 0.f};
    // S^T = K Q^T : lane holds q = lq, k = kf*16 + g*4 + r
    f32x4 sacc[4][2];
#pragma unroll
    for (int kf = 0; kf < 4; ++kf)
#pragma unroll
        for (int qf = 0; qf < 2; ++qf) sacc[kf][qf] = fzero;
#pragma unroll
    for (int kf = 0; kf < 4; ++kf)
#pragma unroll
        for (int qf = 0; qf < 2; ++qf) {
            sacc[kf][qf] = __builtin_amdgcn_mfma_f32_16x16x32_bf16(ka[kf][0], qfr[qf][0], sacc[kf][qf], 0, 0, 0);
            sacc[kf][qf] = __builtin_amdgcn_mfma_f32_16x16x32_bf16(ka[kf][1], qfr[qf][1], sacc[kf][qf], 0, 0, 0);
        }

#pragma unroll
    for (int qf = 0; qf < 2; ++qf) {
        const int qg = wq0 + qf * 16 + lq;
        const bool qok = (qmv[qf] != 0);
        float s[4][4];
        float mx = -1e30f;
#pragma unroll
        for (int kf = 0; kf < 4; ++kf)
#pragma unroll
            for (int r = 0; r < 4; ++r) {
                const int kg = m0 + kf * 16 + g * 4 + r;
                float sv = sacc[kf][qf][r] * 0.125f;   // 1/sqrt(64)
                const bool ok = qok && (km[kf][r] != 0) && (!causal || kg <= qg);
                sv = ok ? sv : -1e30f;
                s[kf][r] = sv;
                mx = fmaxf(mx, sv);
            }
        mx = fmaxf(mx, __shfl_xor(mx, 16));
        mx = fmaxf(mx, __shfl_xor(mx, 32));
        const float mnew = fmaxf(mrow[qf], mx);
        const float scale = __expf(mrow[qf] - mnew);
        float rs = 0.f;
#pragma unroll
        for (int kf = 0; kf < 4; ++kf)
#pragma unroll
            for (int r = 0; r < 4; ++r) {
                const float pv = (s[kf][r] > -1e29f) ? __expf(s[kf][r] - mnew) : 0.f;
                s[kf][r] = pv;
                rs += pv;
            }
        rs += __shfl_xor(rs, 16);
        rs += __shfl_xor(rs, 32);
        lsum[qf] = lsum[qf] * scale + rs;
        mrow[qf] = mnew;
#pragma unroll
        for (int df = 0; df < 4; ++df) oacc[df][qf] *= scale;
#pragma unroll
        for (int kf = 0; kf < 4; ++kf)
#pragma unroll
            for (int r = 0; r < 4; ++r)
                Psw[qf * 16 + lq][kf * 16 + g * 4 + r] = f2b(s[kf][r]);
    }

    // O^T += V^T P^T (Psw is wave-local; no barrier needed)
    bf16x8 pb[2][2];
#pragma unroll
    for (int qf = 0; qf < 2; ++qf)
#pragma unroll
        for (int kc = 0; kc < 2; ++kc)
            pb[qf][kc] = *reinterpret_cast<const bf16x8*>(&Psw[qf * 16 + lq][kc * 32 + g * 8]);
#pragma unroll
    for (int df = 0; df < 4; ++df)
#pragma unroll
        for (int qf = 0; qf < 2; ++qf) {
            oacc[df][qf] = __builtin_amdgcn_mfma_f32_16x16x32_bf16(va[df][0], pb[qf][0], oacc[df][qf], 0, 0, 0);
            oacc[df][qf] = __builtin_amdgcn_mfma_f32_16x16x32_bf16(va[df][1], pb[qf][1], oacc[df][qf], 0, 0, 0);
        }
}

// ===== MFMA flash attention: paired q-tiles (p, 15-p) + double-buffered staging =====
// Block = (b, h, pair p). 4 waves x 32 q-rows per tile. Output f32.
__global__ __launch_bounds__(256, 2) void attn_kernel(const u16* __restrict__ qkv,
                                                      const int* __restrict__ key_mask,
                                                      const int* __restrict__ query_mask,
                                                      const int* __restrict__ causal_p,
                                                      float* __restrict__ out) {
    const int bh = blockIdx.x;
    const int p = blockIdx.y;           // 0..7
    const int b = bh >> 4;
    const int h = bh & 15;
    const int t = threadIdx.x;
    const int lane = t & 63;
    const int wave = t >> 6;
    const int g = lane >> 4;
    const int lq = lane & 15;
    const int causal = causal_p[0];

    __shared__ u16 Ks[64][72];
    __shared__ u16 Vt[64][72];
    __shared__ u16 Ps[4][32][72];

    const int q0A = p * 128;
    const int q0B = (15 - p) * 128;
    const int wq0A = q0A + wave * 32;
    const int wq0B = q0B + wave * 32;

    const f32x4 fzero = {0.f, 0.f, 0.f, 0.f};

    bf16x8 qfrA[2][2], qfrB[2][2];
#pragma unroll
    for (int qf = 0; qf < 2; ++qf)
#pragma unroll
        for (int ks = 0; ks < 2; ++ks) {
            qfrA[qf][ks] = *reinterpret_cast<const bf16x8*>(
                qkv + (size_t)(b * Nseq + wq0A + qf * 16 + lq) * F3 + h * HD + ks * 32 + g * 8);
            qfrB[qf][ks] = *reinterpret_cast<const bf16x8*>(
                qkv + (size_t)(b * Nseq + wq0B + qf * 16 + lq) * F3 + h * HD + ks * 32 + g * 8);
        }

    int qmA[2], qmB[2];
    float mrowA[2], lsumA[2], mrowB[2], lsumB[2];
    f32x4 oaccA[4][2], oaccB[4][2];
#pragma unroll
    for (int qf = 0; qf < 2; ++qf) {
        qmA[qf] = query_mask[b * Nseq + wq0A + qf * 16 + lq];
        qmB[qf] = query_mask[b * Nseq + wq0B + qf * 16 + lq];
        mrowA[qf] = -1e30f; lsumA[qf] = 0.f;
        mrowB[qf] = -1e30f; lsumB[qf] = 0.f;
    }
#pragma unroll
    for (int df = 0; df < 4; ++df)
#pragma unroll
        for (int qf = 0; qf < 2; ++qf) { oaccA[df][qf] = fzero; oaccB[df][qf] = fzero; }

    const int kvendA = causal ? (q0A + 128) : Nseq;
    const int kvendB = causal ? (q0B + 128) : Nseq;   // >= kvendA

    const int sr = t >> 2;           // K staging row 0..63
    const int sc = (t & 3) * 8;      // K staging col {0,8,16,24}

    // prologue: load K/V for m0 = 0 into registers
    bf16x8 kr0, kr1, vr0, vr1;
    {
        const u16* krow = qkv + (size_t)(b * Nseq + 0 + sr) * F3 + DIMc + h * HD;
        kr0 = *reinterpret_cast<const bf16x8*>(krow + sc);
        kr1 = *reinterpret_cast<const bf16x8*>(krow + sc + 32);
        const u16* vrow = qkv + (size_t)(b * Nseq + 0 + lane) * F3 + 2 * DIMc + h * HD + wave * 16;
        vr0 = *reinterpret_cast<const bf16x8*>(vrow);
        vr1 = *reinterpret_cast<const bf16x8*>(vrow + 8);
    }

    for (int m0 = 0; m0 < kvendB; m0 += 64) {
        // ---- write staged regs -> LDS ----
        *reinterpret_cast<bf16x8*>(&Ks[sr][sc])      = kr0;
        *reinterpret_cast<bf16x8*>(&Ks[sr][sc + 32]) = kr1;
#pragma unroll
        for (int e = 0; e < 8; ++e) {
            Vt[wave * 16 + e][lane]     = (u16)vr0[e];
            Vt[wave * 16 + 8 + e][lane] = (u16)vr1[e];
        }
        __syncthreads();

        // ---- prefetch next tile into registers (drains under compute) ----
        if (m0 + 64 < kvendB) {
            const u16* krow = qkv + (size_t)(b * Nseq + m0 + 64 + sr) * F3 + DIMc + h * HD;
            kr0 = *reinterpret_cast<const bf16x8*>(krow + sc);
            kr1 = *reinterpret_cast<const bf16x8*>(krow + sc + 32);
            const u16* vrow = qkv + (size_t)(b * Nseq + m0 + 64 + lane) * F3 + 2 * DIMc + h * HD + wave * 16;
            vr0 = *reinterpret_cast<const bf16x8*>(vrow);
            vr1 = *reinterpret_cast<const bf16x8*>(vrow + 8);
        }

        // ---- shared per-iteration loads ----
        int km[4][4];
#pragma unroll
        for (int kf = 0; kf < 4; ++kf) {
            int4 k4 = *reinterpret_cast<const int4*>(key_mask + b * Nseq + m0 + kf * 16 + g * 4);
            km[kf][0] = k4.x; km[kf][1] = k4.y; km[kf][2] = k4.z; km[kf][3] = k4.w;
        }
        bf16x8 ka[4][2], va[4][2];
#pragma unroll
        for (int kf = 0; kf < 4; ++kf)
#pragma unroll
            for (int ks = 0; ks < 2; ++ks)
                ka[kf][ks] = *reinterpret_cast<const bf16x8*>(&Ks[kf * 16 + lq][ks * 32 + g * 8]);
#pragma unroll
        for (int df = 0; df < 4; ++df)
#pragma unroll
            for (int kc = 0; kc < 2; ++kc)
                va[df][kc] = *reinterpret_cast<const bf16x8*>(&Vt[df * 16 + lq][kc * 32 + g * 8]);

        // ---- tile B (always active), then tile A (while in its causal range) ----
        attn_tile_compute(qfrB, qmB, mrowB, lsumB, oaccB, ka, va, km, wq0B, m0, causal,
                          Ps[wave], g, lq);
        if (m0 < kvendA)
            attn_tile_compute(qfrA, qmA, mrowA, lsumA, oaccA, ka, va, km, wq0A, m0, causal,
                              Ps[wave], g, lq);
        __syncthreads();
    }

    // ---- epilogue ----
#pragma unroll
    for (int qf = 0; qf < 2; ++qf) {
        const float invA = (mrowA[qf] > -1e29f && lsumA[qf] > 0.f) ? 1.f / lsumA[qf] : 0.f;
        const float invB = (mrowB[qf] > -1e29f && lsumB[qf] > 0.f) ? 1.f / lsumB[qf] : 0.f;
        const size_t rowA = (size_t)(b * Nseq + wq0A + qf * 16 + lq) * DIMc + h * HD;
        const size_t rowB = (size_t)(b * Nseq + wq0B + qf * 16 + lq) * DIMc + h * HD;
#pragma unroll
        for (int df = 0; df < 4; ++df)
#pragma unroll
            for (int r = 0; r < 4; ++r) {
                out[rowA + df * 16 + g * 4 + r] = oaccA[df][qf][r] * invA;
                out[rowB + df * 16 + g * 4 + r] = oaccB[df][qf][r] * invB;
            }
    }
}

extern "C" void kernel_launch(void* const* d_in, const int* in_sizes, int n_in,
                              void* d_out, int out_size, void* d_ws, size_t ws_size,
                              hipStream_t stream) {
    const float* x = (const float*)d_in[0];       // [4,2048,1024] f32
    const float* W = (const float*)d_in[1];       // [3072,1024] f32

    char* ws = (char*)d_ws;
    int* km_n = (int*)(ws);
    int* qm_n = (int*)(ws + 32 * 1024);
    int* ca_n = (int*)(ws + 64 * 1024);
    u16* qkv  = (u16*)(ws + (size_t)1024 * 1024);             // 48 MiB
    u16* xb   = (u16*)(ws + (size_t)49 * 1024 * 1024);        // 16 MiB
    u16* wb   = (u16*)(ws + (size_t)65 * 1024 * 1024);        //  6 MiB

    const int nm = Bdim * Nseq;
    norm_mask_kernel<<<(nm + 255) / 256, 256, 0, stream>>>(d_in[2], nm, km_n);
    norm_mask_kernel<<<(nm + 255) / 256, 256, 0, stream>>>(d_in[3], nm, qm_n);
    norm_mask_kernel<<<1, 256, 0, stream>>>(d_in[4], 1, ca_n);

    const int nx4 = (Mrows * DIMc) / 4;
    const int nw4 = (F3 * DIMc) / 4;
    cast_f32_bf16_kernel<<<(nx4 + 255) / 256, 256, 0, stream>>>(x, xb, nx4);
    cast_f32_bf16_kernel<<<(nw4 + 255) / 256, 256, 0, stream>>>(W, wb, nw4);

    qkv_gemm_kernel<<<dim3(Mrows / 128, F3 / 128), 256, 0, stream>>>(xb, wb, qkv);

    attn_kernel<<<dim3(Bdim * NH, 8), 256, 0, stream>>>(qkv, km_n, qm_n, ca_n,
                                                        (float*)d_out);
}